// Round 5
// baseline (141.237 us; speedup 1.0000x reference)
//
#include <hip/hip_runtime.h>
#include <math.h>

// ---------------------------------------------------------------------------
// Attention_2010044694851: x[4,2048,1024] fp32, w_qkv[1536,1024], w_out[1024,512],
// b_out[1024] -> out[4,2048,1024] fp32.
// bf16 MFMA pipeline: cvt -> QKV GEMM (V written transposed in epilogue) ->
// causal sim GEMM -> softmax -> PV GEMM -> proj GEMM.
// GEMM core: 2-buffer depth-1 pipeline, 5-6 blocks/CU occupancy (m97/m114
// route), swizzled conflict-free LDS, setprio MFMA.
// ---------------------------------------------------------------------------

typedef __attribute__((ext_vector_type(8))) short bf16x8_t;
typedef __attribute__((ext_vector_type(4))) float f32x4_t;

__device__ __forceinline__ unsigned short f2bf(float f) {
  unsigned int u = __float_as_uint(f);
  u = (u + 0x7FFFu + ((u >> 16) & 1u)) >> 16;
  return (unsigned short)u;
}
__device__ __forceinline__ float bf2f(unsigned short h) {
  return __uint_as_float(((unsigned int)h) << 16);
}

// ---------------------------------------------------------------------------
// fused fp32 -> bf16 conversion for all three inputs (one launch)
// ---------------------------------------------------------------------------
__global__ __launch_bounds__(256) void cvt_all(
    const float* __restrict__ x, unsigned short* __restrict__ xb, int nx,
    const float* __restrict__ w1, unsigned short* __restrict__ w1b, int n1,
    const float* __restrict__ w2, unsigned short* __restrict__ w2b, int n2) {
  const int stride = gridDim.x * blockDim.x * 4;
  const int t0 = (blockIdx.x * blockDim.x + threadIdx.x) * 4;
  for (int i = t0; i < nx; i += stride) {
    float4 f = *(const float4*)(x + i);
    ushort4 u;
    u.x = f2bf(f.x); u.y = f2bf(f.y); u.z = f2bf(f.z); u.w = f2bf(f.w);
    *(ushort4*)(xb + i) = u;
  }
  for (int i = t0; i < n1; i += stride) {
    float4 f = *(const float4*)(w1 + i);
    ushort4 u;
    u.x = f2bf(f.x); u.y = f2bf(f.y); u.z = f2bf(f.z); u.w = f2bf(f.w);
    *(ushort4*)(w1b + i) = u;
  }
  for (int i = t0; i < n2; i += stride) {
    float4 f = *(const float4*)(w2 + i);
    ushort4 u;
    u.x = f2bf(f.x); u.y = f2bf(f.y); u.z = f2bf(f.z); u.w = f2bf(f.w);
    *(ushort4*)(w2b + i) = u;
  }
}

// ---------------------------------------------------------------------------
// Causal row softmax in-place on sim [4][2048][2048] bf16. One wave per row;
// zero-fills to the 128-tile bound so PV can run full tiles with a K limit.
// ---------------------------------------------------------------------------
__global__ __launch_bounds__(256) void softmax_causal(unsigned short* __restrict__ sim) {
  const int lane = threadIdx.x & 63;
  const int rowg = blockIdx.x * 4 + (threadIdx.x >> 6);
  const int i = rowg & 2047;
  unsigned short* row = sim + (size_t)rowg * 2048;
  const int nv = i + 1;
  const int tb = ((i >> 7) + 1) << 7;
  const int nc = (nv + 255) >> 8;
  const int ns = (tb + 255) >> 8;

  float v[32];
  float m = -1e30f;
#pragma unroll
  for (int c = 0; c < 8; ++c) {
    if (c < nc) {
      const int j0 = c * 256 + lane * 4;
      ushort4 u = *(const ushort4*)(row + j0);
      float f0 = bf2f(u.x), f1 = bf2f(u.y), f2 = bf2f(u.z), f3 = bf2f(u.w);
      v[c * 4 + 0] = (j0 + 0 < nv) ? f0 : -1e30f;
      v[c * 4 + 1] = (j0 + 1 < nv) ? f1 : -1e30f;
      v[c * 4 + 2] = (j0 + 2 < nv) ? f2 : -1e30f;
      v[c * 4 + 3] = (j0 + 3 < nv) ? f3 : -1e30f;
      m = fmaxf(m, fmaxf(fmaxf(v[c * 4], v[c * 4 + 1]), fmaxf(v[c * 4 + 2], v[c * 4 + 3])));
    }
  }
#pragma unroll
  for (int s = 32; s >= 1; s >>= 1) m = fmaxf(m, __shfl_xor(m, s));
  float sum = 0.f;
#pragma unroll
  for (int c = 0; c < 8; ++c) {
    if (c < nc) {
#pragma unroll
      for (int e = 0; e < 4; ++e) {
        float p = __expf(v[c * 4 + e] - m);
        v[c * 4 + e] = p;
        sum += p;
      }
    }
  }
#pragma unroll
  for (int s = 32; s >= 1; s >>= 1) sum += __shfl_xor(sum, s);
  const float inv = 1.0f / sum;
#pragma unroll
  for (int c = 0; c < 8; ++c) {
    if (c < ns) {
      const int j0 = c * 256 + lane * 4;
      ushort4 u;
      if (c < nc) {
        u.x = f2bf(v[c * 4 + 0] * inv);
        u.y = f2bf(v[c * 4 + 1] * inv);
        u.z = f2bf(v[c * 4 + 2] * inv);
        u.w = f2bf(v[c * 4 + 3] * inv);
      } else {
        u.x = u.y = u.z = u.w = 0;
      }
      *(ushort4*)(row + j0) = u;
    }
  }
}

// ---------------------------------------------------------------------------
// bf16 B^T GEMM: C[M,N] = A[M,K] * B[N,K]^T. Tile BMxBN (mult of 64), BK=32,
// 4 waves (2x2), per-wave (BM/2)x(BN/2). 2 LDS buffers, depth-1 pipeline:
// stage(kt+1) right after the iter-kt barrier (race-free: all waves drained
// their iter-(kt-1) ds_reads via lgkmcnt(0) before reaching that barrier).
// Small LDS (32KB at 128x128) -> 5 blocks/CU; co-resident blocks de-phase and
// hide each other's stage/barrier stalls (m97/m114 occupancy route).
// LDS slot swizzle: phys16Bslot = slot ^ ((row>>1)&3), on BOTH stage-src and
// ds_read (rule 21). EPI: 0 QKV scatter (q*scale | k | V transposed)
//                       1 sim bf16   2 attn-out bf16   3 fp32+bias
// ---------------------------------------------------------------------------
template <int EPI, int BM, int BN>
__global__ __launch_bounds__(256) void gemm_bt(
    const unsigned short* __restrict__ A, const unsigned short* __restrict__ B,
    int M, int N, int K, long strideA, long strideB, int klim, int causal,
    void* __restrict__ O0, void* __restrict__ O1, void* __restrict__ O2,
    const float* __restrict__ bias, float qscale) {
  const int bm = blockIdx.x, bn = blockIdx.y, bz = blockIdx.z;
  if (causal && bn > bm) return;
  const int tid = threadIdx.x, lane = tid & 63, wave = tid >> 6;
  const int wr = wave >> 1, wc = wave & 1;
  constexpr int FM = BM / 32, FN = BN / 32;  // 16x16 frags per wave
  constexpr int AR = BM / 64, BR = BN / 64;  // 4KB staging rounds

  __shared__ alignas(16) unsigned short As[2][BM * 32];
  __shared__ alignas(16) unsigned short Bs[2][BN * 32];

  const unsigned short* Ab = A + (size_t)bz * strideA + (size_t)bm * BM * K;
  const unsigned short* Bb = B + (size_t)bz * strideB + (size_t)bn * BN * K;

  const int kmax = klim ? min(K, (bm + 1) * BM) : K;
  const int nkt = kmax >> 5;

  auto stage = [&](int buf, int kt) {
    const int loff = tid * 16;
#pragma unroll
    for (int i = 0; i < AR; ++i) {
      const int o = i * 4096 + loff;
      const int r = o >> 6;
      const int sl = ((o >> 4) & 3) ^ ((r >> 1) & 3);  // logical slot for phys o
      __builtin_amdgcn_global_load_lds(
          (const __attribute__((address_space(1))) void*)(
              (const char*)(Ab + (size_t)r * K) + (size_t)kt * 64 + sl * 16),
          (__attribute__((address_space(3))) void*)((char*)As[buf] + o), 16, 0, 0);
    }
#pragma unroll
    for (int i = 0; i < BR; ++i) {
      const int o = i * 4096 + loff;
      const int r = o >> 6;
      const int sl = ((o >> 4) & 3) ^ ((r >> 1) & 3);
      __builtin_amdgcn_global_load_lds(
          (const __attribute__((address_space(1))) void*)(
              (const char*)(Bb + (size_t)r * K) + (size_t)kt * 64 + sl * 16),
          (__attribute__((address_space(3))) void*)((char*)Bs[buf] + o), 16, 0, 0);
    }
  };

  f32x4_t acc[FM][FN] = {};

  stage(0, 0);
  for (int kt = 0; kt < nkt; ++kt) {
    const int cur = kt & 1;
    asm volatile("s_waitcnt vmcnt(0)" ::: "memory");  // tile kt landed
    __builtin_amdgcn_s_barrier();
    if (kt + 1 < nkt) stage(cur ^ 1, kt + 1);  // overwrites tile kt-1: safe post-barrier

    bf16x8_t av[FM], bv[FN];
#pragma unroll
    for (int f = 0; f < FM; ++f) {
      const int row = wr * (BM / 2) + f * 16 + (lane & 15);
      const int sp = (lane >> 4) ^ ((row >> 1) & 3);
      av[f] = *(const bf16x8_t*)((const char*)As[cur] + row * 64 + sp * 16);
    }
#pragma unroll
    for (int f = 0; f < FN; ++f) {
      const int row = wc * (BN / 2) + f * 16 + (lane & 15);
      const int sp = (lane >> 4) ^ ((row >> 1) & 3);
      bv[f] = *(const bf16x8_t*)((const char*)Bs[cur] + row * 64 + sp * 16);
    }
    asm volatile("s_waitcnt lgkmcnt(0)" ::: "memory");
    __builtin_amdgcn_sched_barrier(0);
    __builtin_amdgcn_s_setprio(1);
#pragma unroll
    for (int fi = 0; fi < FM; ++fi)
#pragma unroll
      for (int fj = 0; fj < FN; ++fj)
        acc[fi][fj] = __builtin_amdgcn_mfma_f32_16x16x32_bf16(av[fi], bv[fj], acc[fi][fj], 0, 0, 0);
    __builtin_amdgcn_s_setprio(0);
    __builtin_amdgcn_sched_barrier(0);
  }

#pragma unroll
  for (int fi = 0; fi < FM; ++fi) {
    const int row_l = wr * (BM / 2) + fi * 16 + ((lane >> 4) << 2);
#pragma unroll
    for (int fj = 0; fj < FN; ++fj) {
      const int col = bn * BN + wc * (BN / 2) + fj * 16 + (lane & 15);
      if constexpr (EPI == 0) {
        const int row0 = bm * BM + row_l;
        if (col < 512) {
#pragma unroll
          for (int r = 0; r < 4; ++r)
            ((unsigned short*)O0)[(size_t)(row0 + r) * 512 + col] =
                f2bf(acc[fi][fj][r] * qscale);
        } else if (col < 1024) {
#pragma unroll
          for (int r = 0; r < 4; ++r)
            ((unsigned short*)O1)[(size_t)(row0 + r) * 512 + (col - 512)] =
                f2bf(acc[fi][fj][r]);
        } else {
          // V transposed: vtb[b][e][n], e = col-1024, n = row within batch.
          const int e = col - 1024;
          const int b = row0 >> 11, n0 = row0 & 2047;
          ushort4 u;
          u.x = f2bf(acc[fi][fj][0]);
          u.y = f2bf(acc[fi][fj][1]);
          u.z = f2bf(acc[fi][fj][2]);
          u.w = f2bf(acc[fi][fj][3]);
          *(ushort4*)((unsigned short*)O2 + ((size_t)b * 512 + e) * 2048 + n0) = u;
        }
      } else {
#pragma unroll
        for (int r = 0; r < 4; ++r) {
          const int row = bm * BM + row_l + r;
          float v = acc[fi][fj][r];
          if constexpr (EPI == 1) {
            ((unsigned short*)O0)[(size_t)bz * 2048 * 2048 + (size_t)row * 2048 + col] = f2bf(v);
          } else if constexpr (EPI == 2) {
            ((unsigned short*)O0)[(size_t)bz * 2048 * 512 + (size_t)row * 512 + col] = f2bf(v);
          } else {
            ((float*)O0)[(size_t)row * 1024 + col] = v + bias[col];
          }
        }
      }
    }
  }
}

// ---------------------------------------------------------------------------
extern "C" void kernel_launch(void* const* d_in, const int* in_sizes, int n_in,
                              void* d_out, int out_size, void* d_ws, size_t ws_size,
                              hipStream_t stream) {
  const float* x = (const float*)d_in[0];
  const float* w_qkv = (const float*)d_in[1];
  const float* w_out = (const float*)d_in[2];
  const float* b_out = (const float*)d_in[3];
  float* out = (float*)d_out;

  char* ws = (char*)d_ws;
  size_t off = 0;
  auto alloc = [&](size_t bytes) {
    size_t o = off;
    off += (bytes + 255) & ~(size_t)255;
    return o;
  };
  unsigned short* xb = (unsigned short*)(ws + alloc((size_t)8192 * 1024 * 2));
  unsigned short* wqkvb = (unsigned short*)(ws + alloc((size_t)1536 * 1024 * 2));
  unsigned short* woutb = (unsigned short*)(ws + alloc((size_t)1024 * 512 * 2));
  unsigned short* qb = (unsigned short*)(ws + alloc((size_t)8192 * 512 * 2));
  unsigned short* kb = (unsigned short*)(ws + alloc((size_t)8192 * 512 * 2));
  unsigned short* vtb = (unsigned short*)(ws + alloc((size_t)8192 * 512 * 2));
  unsigned short* sim = (unsigned short*)(ws + alloc((size_t)4 * 2048 * 2048 * 2));
  unsigned short* ao = (unsigned short*)(ws + alloc((size_t)8192 * 512 * 2));

  const float scale = 1.0f / sqrtf(512.0f);

  cvt_all<<<2048, 256, 0, stream>>>(x, xb, 8192 * 1024, w_qkv, wqkvb, 1536 * 1024,
                                    w_out, woutb, 1024 * 512);

  // QKV: [8192,1536] = xb[8192,1024] * wqkvb^T; V written transposed.
  // 32KB LDS -> 5 blocks/CU.
  gemm_bt<0, 128, 128><<<dim3(64, 12, 1), 256, 0, stream>>>(
      xb, wqkvb, 8192, 1536, 1024, 0, 0, 0, 0, qb, kb, vtb, nullptr, scale);

  // sim = q*scale @ k^T, causal tile skip
  gemm_bt<1, 128, 128><<<dim3(16, 16, 4), 256, 0, stream>>>(
      qb, kb, 2048, 2048, 512, (long)2048 * 512, (long)2048 * 512,
      0, 1, sim, nullptr, nullptr, nullptr, 0.f);

  softmax_causal<<<2048, 256, 0, stream>>>(sim);

  // attn @ v : 128x64 tile (24KB LDS -> 6 blocks/CU), K causal-limited
  gemm_bt<2, 128, 64><<<dim3(16, 8, 4), 256, 0, stream>>>(
      sim, vtb, 2048, 512, 2048, (long)2048 * 2048, (long)512 * 2048,
      1, 0, ao, nullptr, nullptr, nullptr, 0.f);

  // out = ao @ w_out^T + b
  gemm_bt<3, 128, 128><<<dim3(64, 8, 1), 256, 0, stream>>>(
      ao, woutb, 8192, 1024, 512, 0, 0, 0, 0, out, nullptr, nullptr, b_out, 0.f);
}

// Round 6
// 134.203 us; speedup vs baseline: 1.0524x; 1.0524x over previous
//
#include <hip/hip_runtime.h>
#include <math.h>

// ---------------------------------------------------------------------------
// Attention_2010044694851: x[4,2048,1024] fp32, w_qkv[1536,1024], w_out[1024,512],
// b_out[1024] -> out[4,2048,1024] fp32.
// bf16 MFMA pipeline: cvt -> QKV GEMM (V written transposed in epilogue) ->
// causal sim GEMM -> softmax -> PV GEMM -> proj GEMM.
// GEMM core: 3-buffer depth-2 counted-vmcnt pipeline (R4-proven), swizzled
// conflict-free LDS, setprio MFMA, NO scheduler pins (compiler emits
// fine-grained lgkmcnt interleave of ds_read with MFMA — m97 behavior).
// ---------------------------------------------------------------------------

typedef __attribute__((ext_vector_type(8))) short bf16x8_t;
typedef __attribute__((ext_vector_type(4))) float f32x4_t;

__device__ __forceinline__ unsigned short f2bf(float f) {
  unsigned int u = __float_as_uint(f);
  u = (u + 0x7FFFu + ((u >> 16) & 1u)) >> 16;
  return (unsigned short)u;
}
__device__ __forceinline__ float bf2f(unsigned short h) {
  return __uint_as_float(((unsigned int)h) << 16);
}

template <int N>
__device__ __forceinline__ void wait_vmcnt() {
  // memory clobber = the ONLY fence in the K-loop: stops the compiler from
  // hoisting ds_reads above the point where the staged tile is guaranteed
  // landed (it cannot see gload_lds -> ds_read dependencies itself).
  if constexpr (N == 0) asm volatile("s_waitcnt vmcnt(0)" ::: "memory");
  else if constexpr (N == 3) asm volatile("s_waitcnt vmcnt(3)" ::: "memory");
  else if constexpr (N == 4) asm volatile("s_waitcnt vmcnt(4)" ::: "memory");
  else if constexpr (N == 5) asm volatile("s_waitcnt vmcnt(5)" ::: "memory");
  else if constexpr (N == 6) asm volatile("s_waitcnt vmcnt(6)" ::: "memory");
}

// ---------------------------------------------------------------------------
// fused fp32 -> bf16 conversion for all three inputs (one launch)
// ---------------------------------------------------------------------------
__global__ __launch_bounds__(256) void cvt_all(
    const float* __restrict__ x, unsigned short* __restrict__ xb, int nx,
    const float* __restrict__ w1, unsigned short* __restrict__ w1b, int n1,
    const float* __restrict__ w2, unsigned short* __restrict__ w2b, int n2) {
  const int stride = gridDim.x * blockDim.x * 4;
  const int t0 = (blockIdx.x * blockDim.x + threadIdx.x) * 4;
  for (int i = t0; i < nx; i += stride) {
    float4 f = *(const float4*)(x + i);
    ushort4 u;
    u.x = f2bf(f.x); u.y = f2bf(f.y); u.z = f2bf(f.z); u.w = f2bf(f.w);
    *(ushort4*)(xb + i) = u;
  }
  for (int i = t0; i < n1; i += stride) {
    float4 f = *(const float4*)(w1 + i);
    ushort4 u;
    u.x = f2bf(f.x); u.y = f2bf(f.y); u.z = f2bf(f.z); u.w = f2bf(f.w);
    *(ushort4*)(w1b + i) = u;
  }
  for (int i = t0; i < n2; i += stride) {
    float4 f = *(const float4*)(w2 + i);
    ushort4 u;
    u.x = f2bf(f.x); u.y = f2bf(f.y); u.z = f2bf(f.z); u.w = f2bf(f.w);
    *(ushort4*)(w2b + i) = u;
  }
}

// ---------------------------------------------------------------------------
// Causal row softmax in-place on sim [4][2048][2048] bf16. One wave per row;
// zero-fills to the 128-tile bound so PV can run full tiles with a K limit.
// ---------------------------------------------------------------------------
__global__ __launch_bounds__(256) void softmax_causal(unsigned short* __restrict__ sim) {
  const int lane = threadIdx.x & 63;
  const int rowg = blockIdx.x * 4 + (threadIdx.x >> 6);
  const int i = rowg & 2047;
  unsigned short* row = sim + (size_t)rowg * 2048;
  const int nv = i + 1;
  const int tb = ((i >> 7) + 1) << 7;
  const int nc = (nv + 255) >> 8;
  const int ns = (tb + 255) >> 8;

  float v[32];
  float m = -1e30f;
#pragma unroll
  for (int c = 0; c < 8; ++c) {
    if (c < nc) {
      const int j0 = c * 256 + lane * 4;
      ushort4 u = *(const ushort4*)(row + j0);
      float f0 = bf2f(u.x), f1 = bf2f(u.y), f2 = bf2f(u.z), f3 = bf2f(u.w);
      v[c * 4 + 0] = (j0 + 0 < nv) ? f0 : -1e30f;
      v[c * 4 + 1] = (j0 + 1 < nv) ? f1 : -1e30f;
      v[c * 4 + 2] = (j0 + 2 < nv) ? f2 : -1e30f;
      v[c * 4 + 3] = (j0 + 3 < nv) ? f3 : -1e30f;
      m = fmaxf(m, fmaxf(fmaxf(v[c * 4], v[c * 4 + 1]), fmaxf(v[c * 4 + 2], v[c * 4 + 3])));
    }
  }
#pragma unroll
  for (int s = 32; s >= 1; s >>= 1) m = fmaxf(m, __shfl_xor(m, s));
  float sum = 0.f;
#pragma unroll
  for (int c = 0; c < 8; ++c) {
    if (c < nc) {
#pragma unroll
      for (int e = 0; e < 4; ++e) {
        float p = __expf(v[c * 4 + e] - m);
        v[c * 4 + e] = p;
        sum += p;
      }
    }
  }
#pragma unroll
  for (int s = 32; s >= 1; s >>= 1) sum += __shfl_xor(sum, s);
  const float inv = 1.0f / sum;
#pragma unroll
  for (int c = 0; c < 8; ++c) {
    if (c < ns) {
      const int j0 = c * 256 + lane * 4;
      ushort4 u;
      if (c < nc) {
        u.x = f2bf(v[c * 4 + 0] * inv);
        u.y = f2bf(v[c * 4 + 1] * inv);
        u.z = f2bf(v[c * 4 + 2] * inv);
        u.w = f2bf(v[c * 4 + 3] * inv);
      } else {
        u.x = u.y = u.z = u.w = 0;
      }
      *(ushort4*)(row + j0) = u;
    }
  }
}

// ---------------------------------------------------------------------------
// bf16 B^T GEMM: C[M,N] = A[M,K] * B[N,K]^T. Tile BMxBN (mult of 64), BK=32,
// 4 waves (2x2), per-wave (BM/2)x(BN/2). 3 LDS buffers, 2 tiles in flight,
// steady-state wait = vmcnt(loads/tile) — never 0 in the main loop.
// Race ledger: iter kt's barrier is crossed only after each wave's iter-(kt-1)
// ds_reads have completed (their MFMA consumers precede the barrier, compiler
// inserts the lgkm waits); stage(kt+2) overwrites tile (kt-1)'s buffer after
// that barrier -> safe. LDS slot swizzle phys16Bslot = slot ^ ((row>>1)&3)
// applied to BOTH stage-source and ds_read (rule 21); conflicts measured 0.
// EPI: 0 QKV scatter (q*scale | k | V transposed)  1 sim  2 attn-out  3 fp32+bias
// ---------------------------------------------------------------------------
template <int EPI, int BM, int BN>
__global__ __launch_bounds__(256) void gemm_bt(
    const unsigned short* __restrict__ A, const unsigned short* __restrict__ B,
    int M, int N, int K, long strideA, long strideB, int klim, int causal,
    void* __restrict__ O0, void* __restrict__ O1, void* __restrict__ O2,
    const float* __restrict__ bias, float qscale) {
  const int bm = blockIdx.x, bn = blockIdx.y, bz = blockIdx.z;
  if (causal && bn > bm) return;
  const int tid = threadIdx.x, lane = tid & 63, wave = tid >> 6;
  const int wr = wave >> 1, wc = wave & 1;
  constexpr int FM = BM / 32, FN = BN / 32;  // 16x16 frags per wave
  constexpr int AR = BM / 64, BR = BN / 64;  // 4KB staging rounds
  constexpr int L = AR + BR;                 // global_load_lds per tile per thread

  __shared__ alignas(16) unsigned short As[3][BM * 32];
  __shared__ alignas(16) unsigned short Bs[3][BN * 32];

  const unsigned short* Ab = A + (size_t)bz * strideA + (size_t)bm * BM * K;
  const unsigned short* Bb = B + (size_t)bz * strideB + (size_t)bn * BN * K;

  const int kmax = klim ? min(K, (bm + 1) * BM) : K;
  const int nkt = kmax >> 5;

  auto stage = [&](int buf, int kt) {
    const int loff = tid * 16;
#pragma unroll
    for (int i = 0; i < AR; ++i) {
      const int o = i * 4096 + loff;
      const int r = o >> 6;
      const int sl = ((o >> 4) & 3) ^ ((r >> 1) & 3);  // logical slot for phys o
      __builtin_amdgcn_global_load_lds(
          (const __attribute__((address_space(1))) void*)(
              (const char*)(Ab + (size_t)r * K) + (size_t)kt * 64 + sl * 16),
          (__attribute__((address_space(3))) void*)((char*)As[buf] + o), 16, 0, 0);
    }
#pragma unroll
    for (int i = 0; i < BR; ++i) {
      const int o = i * 4096 + loff;
      const int r = o >> 6;
      const int sl = ((o >> 4) & 3) ^ ((r >> 1) & 3);
      __builtin_amdgcn_global_load_lds(
          (const __attribute__((address_space(1))) void*)(
              (const char*)(Bb + (size_t)r * K) + (size_t)kt * 64 + sl * 16),
          (__attribute__((address_space(3))) void*)((char*)Bs[buf] + o), 16, 0, 0);
    }
  };

  f32x4_t acc[FM][FN] = {};

  stage(0, 0);
  if (nkt > 1) stage(1, 1);
  int cur = 0;
  for (int kt = 0; kt < nkt; ++kt) {
    if (kt + 1 < nkt) wait_vmcnt<L>();  // tile kt landed; kt+1 stays in flight
    else wait_vmcnt<0>();
    __builtin_amdgcn_s_barrier();

    bf16x8_t av[FM], bv[FN];
#pragma unroll
    for (int f = 0; f < FM; ++f) {
      const int row = wr * (BM / 2) + f * 16 + (lane & 15);
      const int sp = (lane >> 4) ^ ((row >> 1) & 3);
      av[f] = *(const bf16x8_t*)((const char*)As[cur] + row * 64 + sp * 16);
    }
#pragma unroll
    for (int f = 0; f < FN; ++f) {
      const int row = wc * (BN / 2) + f * 16 + (lane & 15);
      const int sp = (lane >> 4) ^ ((row >> 1) & 3);
      bv[f] = *(const bf16x8_t*)((const char*)Bs[cur] + row * 64 + sp * 16);
    }
    if (kt + 2 < nkt) {
      int nb = cur + 2;
      if (nb >= 3) nb -= 3;
      stage(nb, kt + 2);  // overwrites buf of tile kt-1: safe post-barrier
    }
    // No lgkmcnt(0)/sched_barrier pins here: ds_reads are plain loads, the
    // compiler interleaves them with the MFMAs via fine-grained lgkmcnt.
    __builtin_amdgcn_s_setprio(1);
#pragma unroll
    for (int fi = 0; fi < FM; ++fi)
#pragma unroll
      for (int fj = 0; fj < FN; ++fj)
        acc[fi][fj] = __builtin_amdgcn_mfma_f32_16x16x32_bf16(av[fi], bv[fj], acc[fi][fj], 0, 0, 0);
    __builtin_amdgcn_s_setprio(0);
    cur = (cur + 1 == 3) ? 0 : cur + 1;
  }

#pragma unroll
  for (int fi = 0; fi < FM; ++fi) {
    const int row_l = wr * (BM / 2) + fi * 16 + ((lane >> 4) << 2);
#pragma unroll
    for (int fj = 0; fj < FN; ++fj) {
      const int col = bn * BN + wc * (BN / 2) + fj * 16 + (lane & 15);
      if constexpr (EPI == 0) {
        const int row0 = bm * BM + row_l;
        if (col < 512) {
#pragma unroll
          for (int r = 0; r < 4; ++r)
            ((unsigned short*)O0)[(size_t)(row0 + r) * 512 + col] =
                f2bf(acc[fi][fj][r] * qscale);
        } else if (col < 1024) {
#pragma unroll
          for (int r = 0; r < 4; ++r)
            ((unsigned short*)O1)[(size_t)(row0 + r) * 512 + (col - 512)] =
                f2bf(acc[fi][fj][r]);
        } else {
          // V transposed: vtb[b][e][n], e = col-1024, n = row within batch.
          const int e = col - 1024;
          const int b = row0 >> 11, n0 = row0 & 2047;
          ushort4 u;
          u.x = f2bf(acc[fi][fj][0]);
          u.y = f2bf(acc[fi][fj][1]);
          u.z = f2bf(acc[fi][fj][2]);
          u.w = f2bf(acc[fi][fj][3]);
          *(ushort4*)((unsigned short*)O2 + ((size_t)b * 512 + e) * 2048 + n0) = u;
        }
      } else {
#pragma unroll
        for (int r = 0; r < 4; ++r) {
          const int row = bm * BM + row_l + r;
          float v = acc[fi][fj][r];
          if constexpr (EPI == 1) {
            ((unsigned short*)O0)[(size_t)bz * 2048 * 2048 + (size_t)row * 2048 + col] = f2bf(v);
          } else if constexpr (EPI == 2) {
            ((unsigned short*)O0)[(size_t)bz * 2048 * 512 + (size_t)row * 512 + col] = f2bf(v);
          } else {
            ((float*)O0)[(size_t)row * 1024 + col] = v + bias[col];
          }
        }
      }
    }
  }
}

// ---------------------------------------------------------------------------
extern "C" void kernel_launch(void* const* d_in, const int* in_sizes, int n_in,
                              void* d_out, int out_size, void* d_ws, size_t ws_size,
                              hipStream_t stream) {
  const float* x = (const float*)d_in[0];
  const float* w_qkv = (const float*)d_in[1];
  const float* w_out = (const float*)d_in[2];
  const float* b_out = (const float*)d_in[3];
  float* out = (float*)d_out;

  char* ws = (char*)d_ws;
  size_t off = 0;
  auto alloc = [&](size_t bytes) {
    size_t o = off;
    off += (bytes + 255) & ~(size_t)255;
    return o;
  };
  unsigned short* xb = (unsigned short*)(ws + alloc((size_t)8192 * 1024 * 2));
  unsigned short* wqkvb = (unsigned short*)(ws + alloc((size_t)1536 * 1024 * 2));
  unsigned short* woutb = (unsigned short*)(ws + alloc((size_t)1024 * 512 * 2));
  unsigned short* qb = (unsigned short*)(ws + alloc((size_t)8192 * 512 * 2));
  unsigned short* kb = (unsigned short*)(ws + alloc((size_t)8192 * 512 * 2));
  unsigned short* vtb = (unsigned short*)(ws + alloc((size_t)8192 * 512 * 2));
  unsigned short* sim = (unsigned short*)(ws + alloc((size_t)4 * 2048 * 2048 * 2));
  unsigned short* ao = (unsigned short*)(ws + alloc((size_t)8192 * 512 * 2));

  const float scale = 1.0f / sqrtf(512.0f);

  cvt_all<<<2048, 256, 0, stream>>>(x, xb, 8192 * 1024, w_qkv, wqkvb, 1536 * 1024,
                                    w_out, woutb, 1024 * 512);

  // QKV: [8192,1536] = xb[8192,1024] * wqkvb^T; V written transposed.
  // 48KB LDS -> 3 blocks/CU.
  gemm_bt<0, 128, 128><<<dim3(64, 12, 1), 256, 0, stream>>>(
      xb, wqkvb, 8192, 1536, 1024, 0, 0, 0, 0, qb, kb, vtb, nullptr, scale);

  // sim = q*scale @ k^T, causal tile skip
  gemm_bt<1, 128, 128><<<dim3(16, 16, 4), 256, 0, stream>>>(
      qb, kb, 2048, 2048, 512, (long)2048 * 512, (long)2048 * 512,
      0, 1, sim, nullptr, nullptr, nullptr, 0.f);

  softmax_causal<<<2048, 256, 0, stream>>>(sim);

  // attn @ v : 128x64 tile (36KB LDS -> 4 blocks/CU), K causal-limited
  gemm_bt<2, 128, 64><<<dim3(16, 8, 4), 256, 0, stream>>>(
      sim, vtb, 2048, 512, 2048, (long)2048 * 2048, (long)512 * 2048,
      1, 0, ao, nullptr, nullptr, nullptr, 0.f);

  // out = ao @ w_out^T + b
  gemm_bt<3, 128, 128><<<dim3(64, 8, 1), 256, 0, stream>>>(
      ao, woutb, 8192, 1024, 512, 0, 0, 0, 0, out, nullptr, nullptr, b_out, 0.f);
}